// Round 2
// baseline (693.174 us; speedup 1.0000x reference)
//
#include <hip/hip_runtime.h>

static constexpr int N_NODES = 100000;
static constexpr int N_EDGES = 3200000;
static constexpr int NC16    = N_NODES * 16;         // 1.6M
static constexpr int RB      = 256;                  // nodes per bucket
static constexpr int NB      = (N_NODES + RB - 1) / RB;   // 391 buckets
static constexpr int CAP     = 9000;                 // per-bucket capacity (mean 8192, +9 sigma)
static constexpr int EPB     = 8192;                 // edges per partition block
static constexpr int NPB     = (N_EDGES + EPB - 1) / EPB; // 391 partition blocks

// ---------- small float4 helpers ----------
__device__ __forceinline__ float4 v4fma(float s, float4 w, float4 acc) {
    acc.x = fmaf(s, w.x, acc.x);
    acc.y = fmaf(s, w.y, acc.y);
    acc.z = fmaf(s, w.z, acc.z);
    acc.w = fmaf(s, w.w, acc.w);
    return acc;
}

// broadcast all 4 components from quad-lane KK (v_mov_b32 dpp quad_perm — VALU pipe)
template<int KK>
__device__ __forceinline__ float4 qbcast(float4 a) {
    constexpr int ctrl = KK * 0x55;   // quad_perm:[KK,KK,KK,KK]
    float4 r;
    r.x = __int_as_float(__builtin_amdgcn_mov_dpp(__float_as_int(a.x), ctrl, 0xF, 0xF, true));
    r.y = __int_as_float(__builtin_amdgcn_mov_dpp(__float_as_int(a.y), ctrl, 0xF, 0xF, true));
    r.z = __int_as_float(__builtin_amdgcn_mov_dpp(__float_as_int(a.z), ctrl, 0xF, 0xF, true));
    r.w = __int_as_float(__builtin_amdgcn_mov_dpp(__float_as_int(a.w), ctrl, 0xF, 0xF, true));
    return r;
}

// ew(channels of this lane) += sum over k in [4*KK, 4*KK+4) of a[k] * Wcol[k]
template<int KK>
__device__ __forceinline__ float4 ewstep(float4 a, const float4* wc, float4 ew) {
    float4 v = qbcast<KK>(a);
    ew = v4fma(v.x, wc[4*KK + 0], ew);
    ew = v4fma(v.y, wc[4*KK + 1], ew);
    ew = v4fma(v.z, wc[4*KK + 2], ew);
    ew = v4fma(v.w, wc[4*KK + 3], ew);
    return ew;
}

// ---------------- zero gcount (kernel, NOT hipMemsetAsync — graph-capture-proof) ----
__global__ __launch_bounds__(256)
void k_zero(int* g) {
    int t = blockIdx.x * 256 + threadIdx.x;
    if (t < NB) g[t] = 0;
}

// =====================================================================
// ============ PATH A (new): partition + ew materialization ===========
// =====================================================================
// Group edges by dst bucket (dst>>8). Per-block LDS histogram -> ONE global int
// atomic per (block,bucket) to reserve a contiguous chunk -> scatter records:
//   ewRec4[rec*4+c4]  : 16 fp32 edge weights ew = ea@We + be  (computed ONCE,
//                       bitwise-identical ewstep sequence to the per-pass
//                       recompute, so deg/messages match exactly)
//   metaRec[rec]      : (src<<8) | (dst&255)
// ea is read fully COALESCED here (it was 3x random 64B gathers before).
__global__ __launch_bounds__(512)
void k_part_ew(const int* __restrict__ srcI, const int* __restrict__ dstI,
               const float* __restrict__ ea, const float* __restrict__ We,
               const float* __restrict__ be,
               int* __restrict__ gcount,
               float4* __restrict__ ewRec4, int* __restrict__ metaRec)
{
    __shared__ int hist[NB];
    const int tid  = threadIdx.x;
    const int e0   = blockIdx.x * EPB;
    const int ecnt = min(EPB, N_EDGES - e0);
    for (int t = tid; t < NB; t += 512) hist[t] = 0;
    __syncthreads();
    for (int i = tid; i < ecnt; i += 512) {
        int d = dstI[e0 + i];
        atomicAdd(&hist[d >> 8], 1);              // LDS int atomic (exact, commutative)
    }
    __syncthreads();
    for (int t = tid; t < NB; t += 512) {
        int h = hist[t];
        hist[t] = (h > 0) ? atomicAdd(&gcount[t], h) : 0;   // one global atomic per bucket
    }
    __syncthreads();

    // 4 lanes per edge; lane owns 4 output channels
    const int c4 = tid & 3;
    float4 wc[16];
    const float4* We4 = (const float4*)We;
#pragma unroll
    for (int k = 0; k < 16; ++k) wc[k] = We4[k * 4 + c4];
    const float4 bev = ((const float4*)be)[c4];
    const float4* ea4 = (const float4*)ea;

    for (int i = tid >> 2; i < ecnt; i += 128) {
        const int e = e0 + i;
        const int d = dstI[e];                    // quad reads same addr -> 1 req
        const int s = srcI[e];
        const int b = d >> 8;
        float4 a = ea4[e * 4 + c4];               // coalesced: wave reads 1KB run
        float4 ew = bev;
        ew = ewstep<0>(a, wc, ew);
        ew = ewstep<1>(a, wc, ew);
        ew = ewstep<2>(a, wc, ew);
        ew = ewstep<3>(a, wc, ew);
        int pos = 0;
        if (c4 == 0) pos = atomicAdd(&hist[b], 1);          // LDS cursor
        pos = __shfl(pos, (threadIdx.x & 63) & ~3, 64);     // quad broadcast
        if (pos < CAP) {                          // OOB insurance (never expected)
            const int r = b * CAP + pos;
            ewRec4[r * 4 + c4] = ew;              // quad writes contiguous 64B
            if (c4 == 0) metaRec[r] = (s << 8) | (d & 255);
        }
    }
}

// deg accumulation + dinv (fused). Reads are pure coalesced record streams.
__global__ __launch_bounds__(512)
void k_degdinv(const float4* __restrict__ ewRec4, const int* __restrict__ metaRec,
               const int* __restrict__ gcount, float* __restrict__ dinv)
{
    __shared__ double accS[RB * 16];              // 32 KB
    const int tid = threadIdx.x;
    const int b   = blockIdx.x;
    for (int t = tid; t < RB * 16; t += 512) accS[t] = 0.0;
    const int c4  = tid & 3;
    const int cnt = min(gcount[b], CAP);
    const int base = b * CAP;
    __syncthreads();

#pragma unroll 2
    for (int i = tid >> 2; i < cnt; i += 128) {
        float4 ew = ewRec4[(base + i) * 4 + c4];  // wave: 1KB contiguous
        int m = metaRec[base + i];
        int dl = m & 255;
        double* o = accS + dl * 16 + c4 * 4;
        atomicAdd(o + 0, (double)ew.x);           // ds_add_f64, on-CU
        atomicAdd(o + 1, (double)ew.y);
        atomicAdd(o + 2, (double)ew.z);
        atomicAdd(o + 3, (double)ew.w);
    }
    __syncthreads();

    // fused epilogue: deg -> dinv (adds the +1 self loop), coalesced float4 store
    for (int t = tid; t < RB * 4; t += 512) {
        int nl = t >> 2;
        int ng = b * RB + nl;
        if (ng < N_NODES) {
            const double* s = accS + nl * 16 + (t & 3) * 4;
            float4 o;
            float d0 = (float)s[0] + 1.0f; o.x = (d0 > 0.f) ? rsqrtf(d0 + 1e-12f) : 0.f;
            float d1 = (float)s[1] + 1.0f; o.y = (d1 > 0.f) ? rsqrtf(d1 + 1e-12f) : 0.f;
            float d2 = (float)s[2] + 1.0f; o.z = (d2 > 0.f) ? rsqrtf(d2 + 1e-12f) : 0.f;
            float d3 = (float)s[3] + 1.0f; o.w = (d3 > 0.f) ? rsqrtf(d3 + 1e-12f) : 0.f;
            ((float4*)dinv)[ng * 4 + (t & 3)] = o;
        }
    }
}

// message accumulation: acc[dst] += ew * p[src]
__global__ __launch_bounds__(512)
void k_gather(const float4* __restrict__ ewRec4, const int* __restrict__ metaRec,
              const int* __restrict__ gcount, const float* __restrict__ p,
              float* __restrict__ acc)
{
    __shared__ double accS[RB * 16];              // 32 KB
    const int tid = threadIdx.x;
    const int b   = blockIdx.x;
    for (int t = tid; t < RB * 16; t += 512) accS[t] = 0.0;
    const int c4  = tid & 3;
    const int cnt = min(gcount[b], CAP);
    const int base = b * CAP;
    const float4* p4 = (const float4*)p;
    __syncthreads();

#pragma unroll 2
    for (int i = tid >> 2; i < cnt; i += 128) {
        float4 ew = ewRec4[(base + i) * 4 + c4];  // coalesced stream
        int m = metaRec[base + i];
        float4 pv = p4[((unsigned)m >> 8) * 4 + c4];  // p is 6.4MB, L2/LLC-hot
        int dl = m & 255;
        double* o = accS + dl * 16 + c4 * 4;
        atomicAdd(o + 0, (double)(ew.x * pv.x));
        atomicAdd(o + 1, (double)(ew.y * pv.y));
        atomicAdd(o + 2, (double)(ew.z * pv.z));
        atomicAdd(o + 3, (double)(ew.w * pv.w));
    }
    __syncthreads();

    for (int t = tid; t < RB * 4; t += 512) {
        int nl = t >> 2;
        int ng = b * RB + nl;
        if (ng < N_NODES) {
            const double* s = accS + nl * 16 + (t & 3) * 4;
            float4 o;
            o.x = (float)s[0]; o.y = (float)s[1];
            o.z = (float)s[2]; o.w = (float)s[3];
            ((float4*)acc)[ng * 4 + (t & 3)] = o;
        }
    }
}

// =====================================================================
// ============ PATH B (fallback, proven 680us): old pipeline ==========
// =====================================================================
__global__ __launch_bounds__(256)
void k_part(const int* __restrict__ srcI, const int* __restrict__ dstI,
            int* __restrict__ gcount, int2* __restrict__ meta)
{
    __shared__ int hist[NB];
    const int tid  = threadIdx.x;
    const int e0   = blockIdx.x * EPB;
    const int ecnt = min(EPB, N_EDGES - e0);
    for (int t = tid; t < NB; t += 256) hist[t] = 0;
    __syncthreads();
    for (int i = tid; i < ecnt; i += 256) {
        int d = dstI[e0 + i];
        atomicAdd(&hist[d >> 8], 1);
    }
    __syncthreads();
    for (int t = tid; t < NB; t += 256) {
        int h = hist[t];
        hist[t] = (h > 0) ? atomicAdd(&gcount[t], h) : 0;
    }
    __syncthreads();
    for (int i = tid; i < ecnt; i += 256) {
        int e = e0 + i;
        int d = dstI[e];
        int s = srcI[e];
        int b = d >> 8;
        int pos = atomicAdd(&hist[b], 1);
        if (pos < CAP)
            meta[b * CAP + pos] = make_int2(e, (s << 8) | (d & 255));
    }
}

template<bool HAS_P>
__global__ __launch_bounds__(512)
void k_bucket(const float* __restrict__ ea, const int2* __restrict__ meta,
              const int* __restrict__ gcount, const float* __restrict__ We,
              const float* __restrict__ be, const float* __restrict__ p,
              float* __restrict__ acc)
{
    __shared__ double accS[RB * 16];
    const int tid = threadIdx.x;
    const int b   = blockIdx.x;
    for (int t = tid; t < RB * 16; t += 512) accS[t] = 0.0;

    const int c4 = tid & 3;
    float4 wc[16];
    const float4* We4 = (const float4*)We;
#pragma unroll
    for (int k = 0; k < 16; ++k) wc[k] = We4[k * 4 + c4];
    const float4 bev = ((const float4*)be)[c4];
    const int cnt = min(gcount[b], CAP);
    const int2* ml = meta + b * CAP;
    const float4* ea4 = (const float4*)ea;
    const float4* p4  = (const float4*)p;
    __syncthreads();

#pragma unroll 2
    for (int i = tid >> 2; i < cnt; i += 128) {
        int2 m = ml[i];
        float4 a = ea4[m.x * 4 + c4];
        float4 pv;
        if (HAS_P) pv = p4[((unsigned)m.y >> 8) * 4 + c4];
        const int dl = m.y & 255;
        float4 ew = bev;
        ew = ewstep<0>(a, wc, ew);
        ew = ewstep<1>(a, wc, ew);
        ew = ewstep<2>(a, wc, ew);
        ew = ewstep<3>(a, wc, ew);
        double* o = accS + dl * 16 + c4 * 4;
        if (HAS_P) {
            atomicAdd(o + 0, (double)(ew.x * pv.x));
            atomicAdd(o + 1, (double)(ew.y * pv.y));
            atomicAdd(o + 2, (double)(ew.z * pv.z));
            atomicAdd(o + 3, (double)(ew.w * pv.w));
        } else {
            atomicAdd(o + 0, (double)ew.x);
            atomicAdd(o + 1, (double)ew.y);
            atomicAdd(o + 2, (double)ew.z);
            atomicAdd(o + 3, (double)ew.w);
        }
    }
    __syncthreads();

    for (int t = tid; t < RB * 4; t += 512) {
        int nl = t >> 2;
        int ng = b * RB + nl;
        if (ng < N_NODES) {
            const double* s = accS + nl * 16 + (t & 3) * 4;
            float4 o;
            o.x = (float)s[0]; o.y = (float)s[1];
            o.z = (float)s[2]; o.w = (float)s[3];
            ((float4*)acc)[ng * 4 + (t & 3)] = o;
        }
    }
}

__global__ __launch_bounds__(256)
void k_dinv(float* dd) {
    int t = blockIdx.x * 256 + threadIdx.x;
    if (t < NC16) {
        float d = dd[t] + 1.0f;
        dd[t] = (d > 0.0f) ? rsqrtf(d + 1e-12f) : 0.0f;
    }
}

// =====================================================================
// ===================== shared dense kernels ==========================
// =====================================================================
__global__ __launch_bounds__(256)
void k_xw1(const float* __restrict__ x, const float* __restrict__ W1,
           const float* __restrict__ dinv, float* __restrict__ p)
{
    __shared__ float4 w1s[512];               // [k][c4], k=0..127
    const int t = threadIdx.x;
    const float4* W14 = (const float4*)W1;
    w1s[t]       = W14[t];
    w1s[t + 256] = W14[t + 256];
    __syncthreads();

    const int c4 = t & 3;
    const int nl = t >> 2;                    // 0..63
    const int nb = blockIdx.x * 256;
    int node[4];
    float4 acc[4];
#pragma unroll
    for (int i = 0; i < 4; ++i) {
        node[i] = nb + i * 64 + nl;
        acc[i]  = make_float4(0.f, 0.f, 0.f, 0.f);
    }
    const float4* x4 = (const float4*)x;

    for (int k4 = 0; k4 < 32; ++k4) {
        float4 wv0 = w1s[(k4 * 4 + 0) * 4 + c4];
        float4 wv1 = w1s[(k4 * 4 + 1) * 4 + c4];
        float4 wv2 = w1s[(k4 * 4 + 2) * 4 + c4];
        float4 wv3 = w1s[(k4 * 4 + 3) * 4 + c4];
#pragma unroll
        for (int i = 0; i < 4; ++i) {
            int nn = node[i] < N_NODES ? node[i] : (N_NODES - 1);
            float4 xv = x4[nn * 32 + k4];
            acc[i] = v4fma(xv.x, wv0, acc[i]);
            acc[i] = v4fma(xv.y, wv1, acc[i]);
            acc[i] = v4fma(xv.z, wv2, acc[i]);
            acc[i] = v4fma(xv.w, wv3, acc[i]);
        }
    }
    const float4* dinv4 = (const float4*)dinv;
    float4* pp = (float4*)p;
#pragma unroll
    for (int i = 0; i < 4; ++i) {
        if (node[i] < N_NODES) {
            float4 dv = dinv4[node[i] * 4 + c4];
            float4 o;
            o.x = dv.x * acc[i].x; o.y = dv.y * acc[i].y;
            o.z = dv.z * acc[i].z; o.w = dv.w * acc[i].w;
            pp[node[i] * 4 + c4] = o;
        }
    }
}

__global__ __launch_bounds__(256)
void k_mid(const float* __restrict__ accA, const float* __restrict__ dinv,
           const float* __restrict__ W2, const float* __restrict__ b1,
           float* __restrict__ p)
{
    const int tid = blockIdx.x * 256 + threadIdx.x;
    const int q   = tid >> 2;                 // node
    if (q >= N_NODES) return;
    const int c4 = threadIdx.x & 3;

    float4 wc[16];
    const float4* W24 = (const float4*)W2;
#pragma unroll
    for (int k = 0; k < 16; ++k) wc[k] = W24[k * 4 + c4];
    const float4 b1v = ((const float4*)b1)[c4];

    const float4 av = ((const float4*)accA)[q * 4 + c4];
    const float4 pv = ((const float4*)p)[q * 4 + c4];
    const float4 dv = ((const float4*)dinv)[q * 4 + c4];

    float4 h1;
    h1.x = fmaxf(fmaf(dv.x, av.x + pv.x, b1v.x), 0.f);
    h1.y = fmaxf(fmaf(dv.y, av.y + pv.y, b1v.y), 0.f);
    h1.z = fmaxf(fmaf(dv.z, av.z + pv.z, b1v.z), 0.f);
    h1.w = fmaxf(fmaf(dv.w, av.w + pv.w, b1v.w), 0.f);

    float4 h2 = make_float4(0.f, 0.f, 0.f, 0.f);
    h2 = ewstep<0>(h1, wc, h2);
    h2 = ewstep<1>(h1, wc, h2);
    h2 = ewstep<2>(h1, wc, h2);
    h2 = ewstep<3>(h1, wc, h2);

    float4 o;
    o.x = dv.x * h2.x; o.y = dv.y * h2.y;
    o.z = dv.z * h2.z; o.w = dv.w * h2.w;
    ((float4*)p)[q * 4 + c4] = o;
}

__global__ __launch_bounds__(256)
void k_out(const float* __restrict__ accB, const float* __restrict__ dinv,
           const float* __restrict__ p, const float* __restrict__ b2,
           float* __restrict__ out)
{
    const int tid = blockIdx.x * 256 + threadIdx.x;
    const int q   = tid >> 2;
    if (q >= N_NODES) return;
    const int c4 = threadIdx.x & 3;
    const float4 b2v = ((const float4*)b2)[c4];
    const float4 av = ((const float4*)accB)[q * 4 + c4];
    const float4 pv = ((const float4*)p)[q * 4 + c4];
    const float4 dv = ((const float4*)dinv)[q * 4 + c4];
    float4 o;
    o.x = fmaf(dv.x, av.x + pv.x, b2v.x);
    o.y = fmaf(dv.y, av.y + pv.y, b2v.y);
    o.z = fmaf(dv.z, av.z + pv.z, b2v.z);
    o.w = fmaf(dv.w, av.w + pv.w, b2v.w);
    ((float4*)out)[q * 4 + c4] = o;
}

extern "C" void kernel_launch(void* const* d_in, const int* in_sizes, int n_in,
                              void* d_out, int out_size, void* d_ws, size_t ws_size,
                              hipStream_t stream)
{
    const float* x   = (const float*)d_in[0];
    const int*   ei  = (const int*)d_in[1];
    const float* ea  = (const float*)d_in[2];
    const float* We  = (const float*)d_in[3];
    const float* be  = (const float*)d_in[4];
    const float* W1  = (const float*)d_in[5];
    const float* b1  = (const float*)d_in[6];
    const float* W2  = (const float*)d_in[7];
    const float* b2  = (const float*)d_in[8];
    float* out = (float*)d_out;

    const int* srcI = ei;
    const int* dstI = ei + N_EDGES;

    // common carve (25.6 MB)
    float* dinv = (float*)d_ws;          // deg -> dinv in place       (6.4 MB)
    float* p    = dinv + NC16;           // p1 -> p2 in place          (6.4 MB)
    float* accA = p + NC16;              //                            (6.4 MB)
    float* accB = accA + NC16;           //                            (6.4 MB)

    // PATH A needs:  common + NB*CAP*(64+4) + NB*4   ~= 265.1 MB
    const size_t needA = (size_t)4 * NC16 * 4
                       + (size_t)NB * CAP * (sizeof(float4) * 4 + sizeof(int))
                       + (size_t)NB * sizeof(int) + 4096;

    const dim3 blk(256);

    if (ws_size >= needA) {
        float4* ewRec4 = (float4*)(accB + NC16);                 // NB*CAP*64B (225.2 MB)
        int*    metaRec = (int*)(ewRec4 + (size_t)NB * CAP * 4); // NB*CAP*4B  (14.1 MB)
        int*    gcount  = metaRec + (size_t)NB * CAP;            // NB ints

        hipLaunchKernelGGL(k_zero, dim3((NB + 255) / 256), blk, 0, stream, gcount);
        hipLaunchKernelGGL(k_part_ew, dim3(NPB), dim3(512), 0, stream,
                           srcI, dstI, ea, We, be, gcount, ewRec4, metaRec);
        hipLaunchKernelGGL(k_degdinv, dim3(NB), dim3(512), 0, stream,
                           ewRec4, metaRec, gcount, dinv);
        hipLaunchKernelGGL(k_xw1, dim3((N_NODES + 255) / 256), blk, 0, stream,
                           x, W1, dinv, p);
        hipLaunchKernelGGL(k_gather, dim3(NB), dim3(512), 0, stream,
                           ewRec4, metaRec, gcount, p, accA);
        hipLaunchKernelGGL(k_mid, dim3((N_NODES * 4 + 255) / 256), blk, 0, stream,
                           accA, dinv, W2, b1, p);
        hipLaunchKernelGGL(k_gather, dim3(NB), dim3(512), 0, stream,
                           ewRec4, metaRec, gcount, p, accB);
        hipLaunchKernelGGL(k_out, dim3((N_NODES * 4 + 255) / 256), blk, 0, stream,
                           accB, dinv, p, b2, out);
    } else {
        // fallback: proven round-0 pipeline (54 MB)
        int2* meta   = (int2*)(accB + NC16);                     // NB*CAP*8B (28.2 MB)
        int*  gcount = (int*)(meta + (size_t)NB * CAP);          // NB ints

        hipLaunchKernelGGL(k_zero, dim3((NB + 255) / 256), blk, 0, stream, gcount);
        hipLaunchKernelGGL(k_part, dim3(NPB), blk, 0, stream, srcI, dstI, gcount, meta);
        hipLaunchKernelGGL((k_bucket<false>), dim3(NB), dim3(512), 0, stream,
                           ea, meta, gcount, We, be, (const float*)nullptr, dinv);
        hipLaunchKernelGGL(k_dinv, dim3(NC16 / 256), blk, 0, stream, dinv);
        hipLaunchKernelGGL(k_xw1, dim3((N_NODES + 255) / 256), blk, 0, stream,
                           x, W1, dinv, p);
        hipLaunchKernelGGL((k_bucket<true>), dim3(NB), dim3(512), 0, stream,
                           ea, meta, gcount, We, be, p, accA);
        hipLaunchKernelGGL(k_mid, dim3((N_NODES * 4 + 255) / 256), blk, 0, stream,
                           accA, dinv, W2, b1, p);
        hipLaunchKernelGGL((k_bucket<true>), dim3(NB), dim3(512), 0, stream,
                           ea, meta, gcount, We, be, p, accB);
        hipLaunchKernelGGL(k_out, dim3((N_NODES * 4 + 255) / 256), blk, 0, stream,
                           accB, dinv, p, b2, out);
    }
}

// Round 3
// 651.390 us; speedup vs baseline: 1.0641x; 1.0641x over previous
//
#include <hip/hip_runtime.h>

static constexpr int N_NODES = 100000;
static constexpr int N_EDGES = 3200000;
static constexpr int NC16    = N_NODES * 16;         // 1.6M
static constexpr int RB      = 128;                  // nodes per bucket
static constexpr int NB      = (N_NODES + RB - 1) / RB;   // 782 buckets
static constexpr int CAP     = 4800;                 // per-bucket cap (mean 4096, +11 sigma)
static constexpr int NPB     = 512;                  // partition blocks
static constexpr int EPB     = (N_EDGES + NPB - 1) / NPB; // 6250 edges/partition block

// ---------- small float4 helpers ----------
__device__ __forceinline__ float4 v4fma(float s, float4 w, float4 acc) {
    acc.x = fmaf(s, w.x, acc.x);
    acc.y = fmaf(s, w.y, acc.y);
    acc.z = fmaf(s, w.z, acc.z);
    acc.w = fmaf(s, w.w, acc.w);
    return acc;
}

// broadcast all 4 components from quad-lane KK (v_mov_b32 dpp quad_perm — VALU pipe)
template<int KK>
__device__ __forceinline__ float4 qbcast(float4 a) {
    constexpr int ctrl = KK * 0x55;   // quad_perm:[KK,KK,KK,KK]
    float4 r;
    r.x = __int_as_float(__builtin_amdgcn_mov_dpp(__float_as_int(a.x), ctrl, 0xF, 0xF, true));
    r.y = __int_as_float(__builtin_amdgcn_mov_dpp(__float_as_int(a.y), ctrl, 0xF, 0xF, true));
    r.z = __int_as_float(__builtin_amdgcn_mov_dpp(__float_as_int(a.z), ctrl, 0xF, 0xF, true));
    r.w = __int_as_float(__builtin_amdgcn_mov_dpp(__float_as_int(a.w), ctrl, 0xF, 0xF, true));
    return r;
}

// ew(channels of this lane) += sum over k in [4*KK, 4*KK+4) of a[k] * Wcol[k]
template<int KK>
__device__ __forceinline__ float4 ewstep(float4 a, const float4* wc, float4 ew) {
    float4 v = qbcast<KK>(a);
    ew = v4fma(v.x, wc[4*KK + 0], ew);
    ew = v4fma(v.y, wc[4*KK + 1], ew);
    ew = v4fma(v.z, wc[4*KK + 2], ew);
    ew = v4fma(v.w, wc[4*KK + 3], ew);
    return ew;
}

// Swizzled fp64 LDS accumulate of 4 channel values for (node dl, channel quad c4).
// Layout: channel c of node dl lives at word dl*16 + ((c + dl) & 15).
// Bank of a double at word W is 2*(W mod 16): the +dl rotation spreads a wave's
// 64 lanes uniformly over all 16 bank-pairs -> conflict-free (was 16-way).
__device__ __forceinline__ void accum4(double* __restrict__ accS, int dl, int c4,
                                       double v0, double v1, double v2, double v3) {
    double* row = accS + dl * 16;
    const int pb = (c4 * 4 + dl) & 15;
    atomicAdd(row + ((pb + 0) & 15), v0);
    atomicAdd(row + ((pb + 1) & 15), v1);
    atomicAdd(row + ((pb + 2) & 15), v2);
    atomicAdd(row + ((pb + 3) & 15), v3);
}

// ---------------- zero gcount (kernel, NOT hipMemsetAsync — graph-capture-proof) ----
__global__ __launch_bounds__(256)
void k_zero(int* g) {
    int t = blockIdx.x * 256 + threadIdx.x;
    if (t < NB) g[t] = 0;
}

// =====================================================================
// ============ PATH A: partition + ew materialization =================
// =====================================================================
// Group edges by dst bucket (dst>>7). Per-block LDS histogram -> ONE global int
// atomic per (block,bucket) to reserve a contiguous chunk -> scatter records:
//   ewRec4[rec*4+c4] : 16 fp32 edge weights ew = ea@We + be (computed once;
//                      bitwise-identical ewstep sequence everywhere)
//   metaRec[rec]     : (src<<7) | (dst&127)
__global__ __launch_bounds__(1024)
void k_part_ew(const int* __restrict__ srcI, const int* __restrict__ dstI,
               const float* __restrict__ ea, const float* __restrict__ We,
               const float* __restrict__ be,
               int* __restrict__ gcount,
               float4* __restrict__ ewRec4, int* __restrict__ metaRec)
{
    __shared__ int hist[NB];
    const int tid  = threadIdx.x;
    const int e0   = blockIdx.x * EPB;
    const int ecnt = min(EPB, N_EDGES - e0);
    for (int t = tid; t < NB; t += 1024) hist[t] = 0;
    __syncthreads();
    for (int i = tid; i < ecnt; i += 1024) {
        int d = dstI[e0 + i];
        atomicAdd(&hist[d >> 7], 1);              // LDS int atomic (exact, commutative)
    }
    __syncthreads();
    for (int t = tid; t < NB; t += 1024) {
        int h = hist[t];
        hist[t] = (h > 0) ? atomicAdd(&gcount[t], h) : 0;   // one global atomic per bucket
    }
    __syncthreads();

    // 4 lanes per edge; lane owns 4 output channels
    const int c4 = tid & 3;
    float4 wc[16];
    const float4* We4 = (const float4*)We;
#pragma unroll
    for (int k = 0; k < 16; ++k) wc[k] = We4[k * 4 + c4];
    const float4 bev = ((const float4*)be)[c4];
    const float4* ea4 = (const float4*)ea;

    for (int i = tid >> 2; i < ecnt; i += 256) {
        const int e = e0 + i;
        const int d = dstI[e];                    // quad reads same addr -> 1 req
        const int s = srcI[e];
        const int b = d >> 7;
        float4 a = ea4[e * 4 + c4];               // coalesced: wave reads 1KB run
        float4 ew = bev;
        ew = ewstep<0>(a, wc, ew);
        ew = ewstep<1>(a, wc, ew);
        ew = ewstep<2>(a, wc, ew);
        ew = ewstep<3>(a, wc, ew);
        int pos = 0;
        if (c4 == 0) pos = atomicAdd(&hist[b], 1);          // LDS cursor
        pos = __shfl(pos, (threadIdx.x & 63) & ~3, 64);     // quad broadcast
        if (pos < CAP) {                          // OOB insurance (never expected)
            const int r = b * CAP + pos;
            ewRec4[r * 4 + c4] = ew;              // quad writes contiguous 64B
            if (c4 == 0) metaRec[r] = (s << 7) | (d & 127);
        }
    }
}

// deg accumulation + dinv (fused). Pure coalesced record streams, swizzled LDS.
__global__ __launch_bounds__(1024)
void k_degdinv(const float4* __restrict__ ewRec4, const int* __restrict__ metaRec,
               const int* __restrict__ gcount, float* __restrict__ dinv)
{
    __shared__ double accS[RB * 16];              // 16 KB
    const int tid = threadIdx.x;
    const int b   = blockIdx.x;
    for (int t = tid; t < RB * 16; t += 1024) accS[t] = 0.0;
    const int c4  = tid & 3;
    const int cnt = min(gcount[b], CAP);
    const int base = b * CAP;
    __syncthreads();

#pragma unroll 2
    for (int i = tid >> 2; i < cnt; i += 256) {
        float4 ew = ewRec4[(base + i) * 4 + c4];  // wave: 1KB contiguous
        int m = metaRec[base + i];
        int dl = m & 127;
        accum4(accS, dl, c4, (double)ew.x, (double)ew.y, (double)ew.z, (double)ew.w);
    }
    __syncthreads();

    // fused epilogue: deg -> dinv (adds the +1 self loop), unswizzled coalesced store
    for (int t = tid; t < RB * 4; t += 1024) {
        int nl = t >> 2;
        int ng = b * RB + nl;
        if (ng < N_NODES) {
            const double* s = accS + nl * 16;
            const int pb = ((t & 3) * 4 + nl) & 15;
            float4 o;
            float d0 = (float)s[(pb + 0) & 15] + 1.0f; o.x = (d0 > 0.f) ? rsqrtf(d0 + 1e-12f) : 0.f;
            float d1 = (float)s[(pb + 1) & 15] + 1.0f; o.y = (d1 > 0.f) ? rsqrtf(d1 + 1e-12f) : 0.f;
            float d2 = (float)s[(pb + 2) & 15] + 1.0f; o.z = (d2 > 0.f) ? rsqrtf(d2 + 1e-12f) : 0.f;
            float d3 = (float)s[(pb + 3) & 15] + 1.0f; o.w = (d3 > 0.f) ? rsqrtf(d3 + 1e-12f) : 0.f;
            ((float4*)dinv)[ng * 4 + (t & 3)] = o;
        }
    }
}

// message accumulation: acc[dst] += ew * p[src]
__global__ __launch_bounds__(1024)
void k_gather(const float4* __restrict__ ewRec4, const int* __restrict__ metaRec,
              const int* __restrict__ gcount, const float* __restrict__ p,
              float* __restrict__ acc)
{
    __shared__ double accS[RB * 16];              // 16 KB
    const int tid = threadIdx.x;
    const int b   = blockIdx.x;
    for (int t = tid; t < RB * 16; t += 1024) accS[t] = 0.0;
    const int c4  = tid & 3;
    const int cnt = min(gcount[b], CAP);
    const int base = b * CAP;
    const float4* p4 = (const float4*)p;
    __syncthreads();

#pragma unroll 2
    for (int i = tid >> 2; i < cnt; i += 256) {
        float4 ew = ewRec4[(base + i) * 4 + c4];  // coalesced stream
        int m = metaRec[base + i];
        float4 pv = p4[((unsigned)m >> 7) * 4 + c4];  // p is 6.4MB, L2/LLC-hot
        int dl = m & 127;
        accum4(accS, dl, c4,
               (double)(ew.x * pv.x), (double)(ew.y * pv.y),
               (double)(ew.z * pv.z), (double)(ew.w * pv.w));
    }
    __syncthreads();

    for (int t = tid; t < RB * 4; t += 1024) {
        int nl = t >> 2;
        int ng = b * RB + nl;
        if (ng < N_NODES) {
            const double* s = accS + nl * 16;
            const int pb = ((t & 3) * 4 + nl) & 15;
            float4 o;
            o.x = (float)s[(pb + 0) & 15];
            o.y = (float)s[(pb + 1) & 15];
            o.z = (float)s[(pb + 2) & 15];
            o.w = (float)s[(pb + 3) & 15];
            ((float4*)acc)[ng * 4 + (t & 3)] = o;
        }
    }
}

// =====================================================================
// ============ PATH B (fallback if ws too small): no ew records =======
// =====================================================================
__global__ __launch_bounds__(1024)
void k_part(const int* __restrict__ srcI, const int* __restrict__ dstI,
            int* __restrict__ gcount, int2* __restrict__ meta)
{
    __shared__ int hist[NB];
    const int tid  = threadIdx.x;
    const int e0   = blockIdx.x * EPB;
    const int ecnt = min(EPB, N_EDGES - e0);
    for (int t = tid; t < NB; t += 1024) hist[t] = 0;
    __syncthreads();
    for (int i = tid; i < ecnt; i += 1024) {
        int d = dstI[e0 + i];
        atomicAdd(&hist[d >> 7], 1);
    }
    __syncthreads();
    for (int t = tid; t < NB; t += 1024) {
        int h = hist[t];
        hist[t] = (h > 0) ? atomicAdd(&gcount[t], h) : 0;
    }
    __syncthreads();
    for (int i = tid; i < ecnt; i += 1024) {
        int e = e0 + i;
        int d = dstI[e];
        int s = srcI[e];
        int b = d >> 7;
        int pos = atomicAdd(&hist[b], 1);
        if (pos < CAP)
            meta[b * CAP + pos] = make_int2(e, (s << 7) | (d & 127));
    }
}

template<bool HAS_P>
__global__ __launch_bounds__(1024)
void k_bucket(const float* __restrict__ ea, const int2* __restrict__ meta,
              const int* __restrict__ gcount, const float* __restrict__ We,
              const float* __restrict__ be, const float* __restrict__ p,
              float* __restrict__ acc)
{
    __shared__ double accS[RB * 16];
    const int tid = threadIdx.x;
    const int b   = blockIdx.x;
    for (int t = tid; t < RB * 16; t += 1024) accS[t] = 0.0;

    const int c4 = tid & 3;
    float4 wc[16];
    const float4* We4 = (const float4*)We;
#pragma unroll
    for (int k = 0; k < 16; ++k) wc[k] = We4[k * 4 + c4];
    const float4 bev = ((const float4*)be)[c4];
    const int cnt = min(gcount[b], CAP);
    const int2* ml = meta + b * CAP;
    const float4* ea4 = (const float4*)ea;
    const float4* p4  = (const float4*)p;
    __syncthreads();

#pragma unroll 2
    for (int i = tid >> 2; i < cnt; i += 256) {
        int2 m = ml[i];
        float4 a = ea4[m.x * 4 + c4];
        float4 pv;
        if (HAS_P) pv = p4[((unsigned)m.y >> 7) * 4 + c4];
        const int dl = m.y & 127;
        float4 ew = bev;
        ew = ewstep<0>(a, wc, ew);
        ew = ewstep<1>(a, wc, ew);
        ew = ewstep<2>(a, wc, ew);
        ew = ewstep<3>(a, wc, ew);
        if (HAS_P) {
            accum4(accS, dl, c4,
                   (double)(ew.x * pv.x), (double)(ew.y * pv.y),
                   (double)(ew.z * pv.z), (double)(ew.w * pv.w));
        } else {
            accum4(accS, dl, c4, (double)ew.x, (double)ew.y, (double)ew.z, (double)ew.w);
        }
    }
    __syncthreads();

    for (int t = tid; t < RB * 4; t += 1024) {
        int nl = t >> 2;
        int ng = b * RB + nl;
        if (ng < N_NODES) {
            const double* s = accS + nl * 16;
            const int pb = ((t & 3) * 4 + nl) & 15;
            float4 o;
            o.x = (float)s[(pb + 0) & 15];
            o.y = (float)s[(pb + 1) & 15];
            o.z = (float)s[(pb + 2) & 15];
            o.w = (float)s[(pb + 3) & 15];
            ((float4*)acc)[ng * 4 + (t & 3)] = o;
        }
    }
}

__global__ __launch_bounds__(256)
void k_dinv(float* dd) {
    int t = blockIdx.x * 256 + threadIdx.x;
    if (t < NC16) {
        float d = dd[t] + 1.0f;
        dd[t] = (d > 0.0f) ? rsqrtf(d + 1e-12f) : 0.0f;
    }
}

// =====================================================================
// ===================== shared dense kernels ==========================
// =====================================================================
__global__ __launch_bounds__(256)
void k_xw1(const float* __restrict__ x, const float* __restrict__ W1,
           const float* __restrict__ dinv, float* __restrict__ p)
{
    __shared__ float4 w1s[512];               // [k][c4], k=0..127
    const int t = threadIdx.x;
    const float4* W14 = (const float4*)W1;
    w1s[t]       = W14[t];
    w1s[t + 256] = W14[t + 256];
    __syncthreads();

    const int c4 = t & 3;
    const int nl = t >> 2;                    // 0..63
    const int nb = blockIdx.x * 256;
    int node[4];
    float4 acc[4];
#pragma unroll
    for (int i = 0; i < 4; ++i) {
        node[i] = nb + i * 64 + nl;
        acc[i]  = make_float4(0.f, 0.f, 0.f, 0.f);
    }
    const float4* x4 = (const float4*)x;

    for (int k4 = 0; k4 < 32; ++k4) {
        float4 wv0 = w1s[(k4 * 4 + 0) * 4 + c4];
        float4 wv1 = w1s[(k4 * 4 + 1) * 4 + c4];
        float4 wv2 = w1s[(k4 * 4 + 2) * 4 + c4];
        float4 wv3 = w1s[(k4 * 4 + 3) * 4 + c4];
#pragma unroll
        for (int i = 0; i < 4; ++i) {
            int nn = node[i] < N_NODES ? node[i] : (N_NODES - 1);
            float4 xv = x4[nn * 32 + k4];
            acc[i] = v4fma(xv.x, wv0, acc[i]);
            acc[i] = v4fma(xv.y, wv1, acc[i]);
            acc[i] = v4fma(xv.z, wv2, acc[i]);
            acc[i] = v4fma(xv.w, wv3, acc[i]);
        }
    }
    const float4* dinv4 = (const float4*)dinv;
    float4* pp = (float4*)p;
#pragma unroll
    for (int i = 0; i < 4; ++i) {
        if (node[i] < N_NODES) {
            float4 dv = dinv4[node[i] * 4 + c4];
            float4 o;
            o.x = dv.x * acc[i].x; o.y = dv.y * acc[i].y;
            o.z = dv.z * acc[i].z; o.w = dv.w * acc[i].w;
            pp[node[i] * 4 + c4] = o;
        }
    }
}

__global__ __launch_bounds__(256)
void k_mid(const float* __restrict__ accA, const float* __restrict__ dinv,
           const float* __restrict__ W2, const float* __restrict__ b1,
           float* __restrict__ p)
{
    const int tid = blockIdx.x * 256 + threadIdx.x;
    const int q   = tid >> 2;                 // node
    if (q >= N_NODES) return;
    const int c4 = threadIdx.x & 3;

    float4 wc[16];
    const float4* W24 = (const float4*)W2;
#pragma unroll
    for (int k = 0; k < 16; ++k) wc[k] = W24[k * 4 + c4];
    const float4 b1v = ((const float4*)b1)[c4];

    const float4 av = ((const float4*)accA)[q * 4 + c4];
    const float4 pv = ((const float4*)p)[q * 4 + c4];
    const float4 dv = ((const float4*)dinv)[q * 4 + c4];

    float4 h1;
    h1.x = fmaxf(fmaf(dv.x, av.x + pv.x, b1v.x), 0.f);
    h1.y = fmaxf(fmaf(dv.y, av.y + pv.y, b1v.y), 0.f);
    h1.z = fmaxf(fmaf(dv.z, av.z + pv.z, b1v.z), 0.f);
    h1.w = fmaxf(fmaf(dv.w, av.w + pv.w, b1v.w), 0.f);

    float4 h2 = make_float4(0.f, 0.f, 0.f, 0.f);
    h2 = ewstep<0>(h1, wc, h2);
    h2 = ewstep<1>(h1, wc, h2);
    h2 = ewstep<2>(h1, wc, h2);
    h2 = ewstep<3>(h1, wc, h2);

    float4 o;
    o.x = dv.x * h2.x; o.y = dv.y * h2.y;
    o.z = dv.z * h2.z; o.w = dv.w * h2.w;
    ((float4*)p)[q * 4 + c4] = o;
}

__global__ __launch_bounds__(256)
void k_out(const float* __restrict__ accB, const float* __restrict__ dinv,
           const float* __restrict__ p, const float* __restrict__ b2,
           float* __restrict__ out)
{
    const int tid = blockIdx.x * 256 + threadIdx.x;
    const int q   = tid >> 2;
    if (q >= N_NODES) return;
    const int c4 = threadIdx.x & 3;
    const float4 b2v = ((const float4*)b2)[c4];
    const float4 av = ((const float4*)accB)[q * 4 + c4];
    const float4 pv = ((const float4*)p)[q * 4 + c4];
    const float4 dv = ((const float4*)dinv)[q * 4 + c4];
    float4 o;
    o.x = fmaf(dv.x, av.x + pv.x, b2v.x);
    o.y = fmaf(dv.y, av.y + pv.y, b2v.y);
    o.z = fmaf(dv.z, av.z + pv.z, b2v.z);
    o.w = fmaf(dv.w, av.w + pv.w, b2v.w);
    ((float4*)out)[q * 4 + c4] = o;
}

extern "C" void kernel_launch(void* const* d_in, const int* in_sizes, int n_in,
                              void* d_out, int out_size, void* d_ws, size_t ws_size,
                              hipStream_t stream)
{
    const float* x   = (const float*)d_in[0];
    const int*   ei  = (const int*)d_in[1];
    const float* ea  = (const float*)d_in[2];
    const float* We  = (const float*)d_in[3];
    const float* be  = (const float*)d_in[4];
    const float* W1  = (const float*)d_in[5];
    const float* b1  = (const float*)d_in[6];
    const float* W2  = (const float*)d_in[7];
    const float* b2  = (const float*)d_in[8];
    float* out = (float*)d_out;

    const int* srcI = ei;
    const int* dstI = ei + N_EDGES;

    // common carve (25.6 MB)
    float* dinv = (float*)d_ws;          // deg -> dinv in place       (6.4 MB)
    float* p    = dinv + NC16;           // p1 -> p2 in place          (6.4 MB)
    float* accA = p + NC16;              //                            (6.4 MB)
    float* accB = accA + NC16;           //                            (6.4 MB)

    // PATH A needs: common + NB*CAP*(64+4) + NB*4  ~= 281 MB
    const size_t needA = (size_t)4 * NC16 * 4
                       + (size_t)NB * CAP * (sizeof(float4) * 4 + sizeof(int))
                       + (size_t)NB * sizeof(int) + 4096;

    const dim3 blk(256);

    if (ws_size >= needA) {
        float4* ewRec4 = (float4*)(accB + NC16);                 // NB*CAP*64B (240 MB)
        int*    metaRec = (int*)(ewRec4 + (size_t)NB * CAP * 4); // NB*CAP*4B  (15 MB)
        int*    gcount  = metaRec + (size_t)NB * CAP;            // NB ints

        hipLaunchKernelGGL(k_zero, dim3((NB + 255) / 256), blk, 0, stream, gcount);
        hipLaunchKernelGGL(k_part_ew, dim3(NPB), dim3(1024), 0, stream,
                           srcI, dstI, ea, We, be, gcount, ewRec4, metaRec);
        hipLaunchKernelGGL(k_degdinv, dim3(NB), dim3(1024), 0, stream,
                           ewRec4, metaRec, gcount, dinv);
        hipLaunchKernelGGL(k_xw1, dim3((N_NODES + 255) / 256), blk, 0, stream,
                           x, W1, dinv, p);
        hipLaunchKernelGGL(k_gather, dim3(NB), dim3(1024), 0, stream,
                           ewRec4, metaRec, gcount, p, accA);
        hipLaunchKernelGGL(k_mid, dim3((N_NODES * 4 + 255) / 256), blk, 0, stream,
                           accA, dinv, W2, b1, p);
        hipLaunchKernelGGL(k_gather, dim3(NB), dim3(1024), 0, stream,
                           ewRec4, metaRec, gcount, p, accB);
        hipLaunchKernelGGL(k_out, dim3((N_NODES * 4 + 255) / 256), blk, 0, stream,
                           accB, dinv, p, b2, out);
    } else {
        // fallback: recompute-ew pipeline (56 MB)
        int2* meta   = (int2*)(accB + NC16);                     // NB*CAP*8B (30 MB)
        int*  gcount = (int*)(meta + (size_t)NB * CAP);          // NB ints

        hipLaunchKernelGGL(k_zero, dim3((NB + 255) / 256), blk, 0, stream, gcount);
        hipLaunchKernelGGL(k_part, dim3(NPB), dim3(1024), 0, stream,
                           srcI, dstI, gcount, meta);
        hipLaunchKernelGGL((k_bucket<false>), dim3(NB), dim3(1024), 0, stream,
                           ea, meta, gcount, We, be, (const float*)nullptr, dinv);
        hipLaunchKernelGGL(k_dinv, dim3(NC16 / 256), blk, 0, stream, dinv);
        hipLaunchKernelGGL(k_xw1, dim3((N_NODES + 255) / 256), blk, 0, stream,
                           x, W1, dinv, p);
        hipLaunchKernelGGL((k_bucket<true>), dim3(NB), dim3(1024), 0, stream,
                           ea, meta, gcount, We, be, p, accA);
        hipLaunchKernelGGL(k_mid, dim3((N_NODES * 4 + 255) / 256), blk, 0, stream,
                           accA, dinv, W2, b1, p);
        hipLaunchKernelGGL((k_bucket<true>), dim3(NB), dim3(1024), 0, stream,
                           ea, meta, gcount, We, be, p, accB);
        hipLaunchKernelGGL(k_out, dim3((N_NODES * 4 + 255) / 256), blk, 0, stream,
                           accB, dinv, p, b2, out);
    }
}